// Round 17
// baseline (102.742 us; speedup 1.0000x reference)
//
#include <hip/hip_runtime.h>
#include <math.h>

#define BSZ 15
#define NA  225
typedef unsigned long long u64;

// weight chain (cndmask, no indexed array)
__device__ __forceinline__ float wtab(int n) {  // n>=1; n>=5 -> 1e5
    return n == 1 ? 5.f : n == 2 ? 50.f : n == 3 ? 500.f : n == 4 ? 5000.f : 100000.f;
}

struct Masks { u64 P[4], O[4]; };   // static-index access only

// extraction with precomputed (q, sh): per-board part only.
template<bool HAS64>
__device__ __forceinline__ void extract2(int q, int sh, const Masks& M, u64 wmask,
                                         int& pc, int& oc)
{
    const u64 Plo = (q & 2) ? ((q & 1) ? M.P[3] : M.P[2]) : ((q & 1) ? M.P[1] : M.P[0]);
    const u64 Phi = (q & 2) ? ((q & 1) ? 0ULL   : M.P[3]) : ((q & 1) ? M.P[2] : M.P[1]);
    const u64 Olo = (q & 2) ? ((q & 1) ? M.O[3] : M.O[2]) : ((q & 1) ? M.O[1] : M.O[0]);
    const u64 Ohi = (q & 2) ? ((q & 1) ? 0ULL   : M.O[3]) : ((q & 1) ? M.O[2] : M.O[1]);
    const u64 xP = (Plo >> sh) | ((Phi << (63 - sh)) << 1);  // sh==0 safe
    const u64 xO = (Olo >> sh) | ((Ohi << (63 - sh)) << 1);
    pc = __popcll(xP & wmask);
    oc = __popcll(xO & wmask);
    if (HAS64) {  // step-16 window spans 65 bits: cell4 = bit sh of hi chunk
        pc += (int)((Phi >> sh) & 1ULL);
        oc += (int)((Ohi >> sh) & 1ULL);
    }
}

// branchless s0 and d. d==95000 uniquely marks pc==4 && oc==0 (win window):
// oc==0 deltas {5,45,450,4500,95000}; pc==0 deltas {5,50,500,5000,100000}; mixed 0.
__device__ __forceinline__ void scoreD(int pc, int oc, float& s0, float& d) {
    const bool z_oc = (oc == 0), z_pc = (pc == 0);
    s0 = z_oc ? (z_pc ? 0.f : wtab(pc)) : (z_pc ? -wtab(oc) : 0.f);
    d  = (z_oc ? wtab(pc + 1) : 0.f) - s0;
}

// One window slot for BOTH boards: address math shared, extraction/score/write x2.
template<int DIV, int CEXTRA, bool HAS64>
__device__ __forceinline__ void doSlot2(int u, bool act, u64 wmask, int toff,
                                        const Masks& M0, const Masks& M1,
                                        float* __restrict__ dw0, float* __restrict__ dw1,
                                        float& base0, float& base1)
{
    const int r = u / DIV;              // compile-time divisor -> magic mul (shared)
    const int c = u % DIV + CEXTRA;
    const int idx = r * BSZ + c;
    const int q = idx >> 6, sh = idx & 63;
    int pc0, oc0, pc1, oc1;
    extract2<HAS64>(q, sh, M0, wmask, pc0, oc0);
    extract2<HAS64>(q, sh, M1, wmask, pc1, oc1);
    float s00, d0, s01, d1;
    scoreD(pc0, oc0, s00, d0);
    scoreD(pc1, oc1, s01, d1);
    if (act) {
        base0 += s00; base1 += s01;
        dw0[toff + u] = d0;
        dw1[toff + u] = d1;
    }
}

// One wave = TWO boards (ILP x2 on every latency chain), 8 boards/block,
// no __syncthreads, no LDS atomics. Gather through per-window d-tables.
__global__ __launch_bounds__(256, 4) void heur_kernel(
    const int* __restrict__ boards, const int* __restrict__ cur,
    const float* __restrict__ pnoise, const float* __restrict__ vnoise,
    float* __restrict__ out, int B)
{
    const int wid  = threadIdx.x >> 6;
    const int lane = threadIdx.x & 63;
    const int bb   = blockIdx.x * 8 + wid * 2;

    // d-tables: [0,165) H, [165,330) V, [330,451) D, [451,572) A; one per board
    __shared__ float sDW[8][572];

    if (bb >= B) return;  // whole wave exits together
    const bool b1ok = (bb + 1 < B);
    const int  b0 = bb, b1 = b1ok ? bb + 1 : bb;

    float* __restrict__ dw0 = sDW[wid * 2];
    float* __restrict__ dw1 = sDW[wid * 2 + 1];

    const int pl0 = cur[b0], op0 = 3 - pl0;
    const int pl1 = cur[b1], op1 = 3 - pl1;
    const int* __restrict__ gb0 = boards + (size_t)b0 * NA;
    const int* __restrict__ gb1 = boards + (size_t)b1 * NA;

    // board cells: lane holds cells lane+64j (chunk j, bit position = lane)
    int v0[4], v1[4];
    v0[0] = gb0[lane]; v0[1] = gb0[lane + 64]; v0[2] = gb0[lane + 128];
    v0[3] = (lane + 192 < NA) ? gb0[lane + 192] : -1;
    v1[0] = gb1[lane]; v1[1] = gb1[lane + 64]; v1[2] = gb1[lane + 128];
    v1[3] = (lane + 192 < NA) ? gb1[lane + 192] : -1;

    // noise loads issued early; latency hides under the VALU window pass
    const float* __restrict__ pn0 = pnoise + (size_t)b0 * NA;
    const float* __restrict__ pn1 = pnoise + (size_t)b1 * NA;
    float pnv0[4], pnv1[4];
    pnv0[0] = pn0[lane]; pnv0[1] = pn0[lane + 64]; pnv0[2] = pn0[lane + 128];
    pnv0[3] = (lane + 192 < NA) ? pn0[lane + 192] : 0.f;
    pnv1[0] = pn1[lane]; pnv1[1] = pn1[lane + 64]; pnv1[2] = pn1[lane + 128];
    pnv1[3] = (lane + 192 < NA) ? pn1[lane + 192] : 0.f;
    const float vnb0 = vnoise[b0], vnb1 = vnoise[b1];

    Masks M0, M1;
    #pragma unroll
    for (int k = 0; k < 4; ++k) {
        M0.P[k] = __ballot(v0[k] == pl0); M0.O[k] = __ballot(v0[k] == op0);
        M1.P[k] = __ballot(v1[k] == pl1); M1.O[k] = __ballot(v1[k] == op1);
    }
    // occupancy chunks for the empty test (M can die after the window pass)
    u64 C0[4], C1[4];
    #pragma unroll
    for (int k = 0; k < 4; ++k) { C0[k] = M0.P[k] | M0.O[k]; C1[k] = M1.P[k] | M1.O[k]; }

    // ---- window pass: 10 slots, addr math shared, both boards per slot ----
    const u64 MH = 0x1FULL;
    const u64 MV = 0x1000200040008001ULL;   // bits 0,15,30,45,60
    const u64 MD = 0x0001000100010001ULL;   // bits 0,16,32,48 (+bit64)
    const u64 MA = 0x0100040010004001ULL;   // bits 0,14,28,42,56
    const bool a2 = lane < 37, a7 = lane < 57;

    float base0 = 0.f, base1 = 0.f;
    doSlot2<11, 0, false>(lane,                 true, MH, 0,   M0, M1, dw0, dw1, base0, base1);
    doSlot2<11, 0, false>(lane + 64,            true, MH, 0,   M0, M1, dw0, dw1, base0, base1);
    doSlot2<11, 0, false>(min(lane + 128, 164), a2,   MH, 0,   M0, M1, dw0, dw1, base0, base1);
    doSlot2<15, 0, false>(lane,                 true, MV, 165, M0, M1, dw0, dw1, base0, base1);
    doSlot2<15, 0, false>(lane + 64,            true, MV, 165, M0, M1, dw0, dw1, base0, base1);
    doSlot2<15, 0, false>(min(lane + 128, 164), a2,   MV, 165, M0, M1, dw0, dw1, base0, base1);
    doSlot2<11, 0, true >(lane,                 true, MD, 330, M0, M1, dw0, dw1, base0, base1);
    doSlot2<11, 0, true >(min(lane + 64, 120),  a7,   MD, 330, M0, M1, dw0, dw1, base0, base1);
    doSlot2<11, 4, false>(lane,                 true, MA, 451, M0, M1, dw0, dw1, base0, base1);
    doSlot2<11, 4, false>(min(lane + 64, 120),  a7,   MA, 451, M0, M1, dw0, dw1, base0, base1);

    __threadfence_block();  // same-wave DS ordering before gather

    // base butterflies, both boards interleaved
    #pragma unroll
    for (int off = 32; off; off >>= 1) {
        base0 += __shfl_xor(base0, off, 64);
        base1 += __shfl_xor(base1, off, 64);
    }

    // ---- per-cell gather: tap addresses shared, reads x2 ----
    float lg0[4], lg1[4];
    float n0 = 0.f, s0 = 0.f, n1 = 0.f, s1 = 0.f;
    #pragma unroll
    for (int j = 0; j < 4; ++j) {
        const int cl = lane + 64 * j;
        float a0 = 0.f, a1 = 0.f;
        bool  w0 = false, w1 = false;
        float l0 = -1000000.f, l1 = -1000000.f;
        if (cl < NA) {
            const int r = cl / BSZ, c = cl % BSZ;   // const divisor -> magic mul
            #pragma unroll
            for (int k = 0; k < 5; ++k) {
                const int wr  = r - k;
                const int wcH = c - k;
                const int wcA = c + k - 4;
                const bool vR = (unsigned)wr  < 11u;
                const bool vH = (unsigned)wcH < 11u;
                const bool vA = (unsigned)wcA < 11u;
                if (vH) {
                    const int i = r * 11 + wcH;
                    const float x0 = dw0[i], x1 = dw1[i];
                    a0 += x0; w0 |= (x0 == 95000.f);
                    a1 += x1; w1 |= (x1 == 95000.f);
                }
                if (vR) {
                    const int i = 165 + wr * 15 + c;
                    const float x0 = dw0[i], x1 = dw1[i];
                    a0 += x0; w0 |= (x0 == 95000.f);
                    a1 += x1; w1 |= (x1 == 95000.f);
                }
                if (vR && vH) {
                    const int i = 330 + wr * 11 + wcH;
                    const float x0 = dw0[i], x1 = dw1[i];
                    a0 += x0; w0 |= (x0 == 95000.f);
                    a1 += x1; w1 |= (x1 == 95000.f);
                }
                if (vR && vA) {
                    const int i = 451 + wr * 11 + wcA;
                    const float x0 = dw0[i], x1 = dw1[i];
                    a0 += x0; w0 |= (x0 == 95000.f);
                    a1 += x1; w1 |= (x1 == 95000.f);
                }
            }
            const u64 c0 = j == 0 ? C0[0] : j == 1 ? C0[1] : j == 2 ? C0[2] : C0[3];
            const u64 c1 = j == 0 ? C1[0] : j == 1 ? C1[1] : j == 2 ? C1[2] : C1[3];
            if (((c0 >> lane) & 1ULL) == 0ULL) l0 = w0 ? 100000.f : base0 + a0;
            if (((c1 >> lane) & 1ULL) == 0ULL) l1 = w1 ? 100000.f : base1 + a1;
        }
        lg0[j] = l0; lg1[j] = l1;
        if (cl < NA && l0 > -100000.f) { n0 += 1.f; s0 += l0; }
        if (cl < NA && l1 > -100000.f) { n1 += 1.f; s1 += l1; }
    }

    // {n,sum} butterflies, both boards interleaved (4 independent chains)
    #pragma unroll
    for (int off = 32; off; off >>= 1) {
        n0 += __shfl_xor(n0, off, 64); s0 += __shfl_xor(s0, off, 64);
        n1 += __shfl_xor(n1, off, 64); s1 += __shfl_xor(s1, off, 64);
    }
    const float mean0 = s0 / fmaxf(n0, 1.f);
    const float mean1 = s1 / fmaxf(n1, 1.f);

    float q0 = 0.f, q1 = 0.f;
    #pragma unroll
    for (int j = 0; j < 4; ++j) {
        const int cl = lane + 64 * j;
        if (cl < NA && lg0[j] > -100000.f) { const float d = lg0[j] - mean0; q0 += d * d; }
        if (cl < NA && lg1[j] > -100000.f) { const float d = lg1[j] - mean1; q1 += d * d; }
    }
    #pragma unroll
    for (int off = 32; off; off >>= 1) {
        q0 += __shfl_xor(q0, off, 64);
        q1 += __shfl_xor(q1, off, 64);
    }
    const float nsc0 = 2.0f * fmaxf(1.f, sqrtf(q0 / fmaxf(n0, 1.f)));
    const float nsc1 = 2.0f * fmaxf(1.f, sqrtf(q1 / fmaxf(n1, 1.f)));
    const bool av0 = n0 > 0.f, av1 = n1 > 0.f;

    float xs0[4], xs1[4];
    float m0 = -INFINITY, m1 = -INFINITY;
    #pragma unroll
    for (int j = 0; j < 4; ++j) {
        const int cl = lane + 64 * j;
        float l0 = lg0[j], l1 = lg1[j];
        if (cl < NA && l0 > -100000.f && av0) l0 += pnv0[j] * nsc0;
        if (cl < NA && l1 > -100000.f && av1) l1 += pnv1[j] * nsc1;
        xs0[j] = l0 * 0.03f; xs1[j] = l1 * 0.03f;
        if (cl < NA) { m0 = fmaxf(m0, xs0[j]); m1 = fmaxf(m1, xs1[j]); }
    }
    #pragma unroll
    for (int off = 32; off; off >>= 1) {
        m0 = fmaxf(m0, __shfl_xor(m0, off, 64));
        m1 = fmaxf(m1, __shfl_xor(m1, off, 64));
    }

    float ev0[4], ev1[4];
    float e0 = 0.f, e1 = 0.f;
    #pragma unroll
    for (int j = 0; j < 4; ++j) {
        const int cl = lane + 64 * j;
        ev0[j] = (cl < NA) ? __expf(xs0[j] - m0) : 0.f;
        ev1[j] = (cl < NA) ? __expf(xs1[j] - m1) : 0.f;
        e0 += ev0[j]; e1 += ev1[j];
    }
    #pragma unroll
    for (int off = 32; off; off >>= 1) {
        e0 += __shfl_xor(e0, off, 64);
        e1 += __shfl_xor(e1, off, 64);
    }
    const float inv0 = 1.f / e0, inv1 = 1.f / e1;

    float* __restrict__ po0 = out + (size_t)b0 * NA;
    float* __restrict__ po1 = out + (size_t)b1 * NA;
    #pragma unroll
    for (int j = 0; j < 4; ++j) {
        const int cl = lane + 64 * j;
        if (cl < NA) {
            po0[cl] = ev0[j] * inv0;
            if (b1ok) po1[cl] = ev1[j] * inv1;
        }
    }

    if (lane == 0) {
        float w = tanhf((base0 + vnb0 * 200.0f) / 3000.0f);
        out[(size_t)B * NA + b0] = fminf(0.95f, fmaxf(-0.95f, w));
        if (b1ok) {
            float y = tanhf((base1 + vnb1 * 200.0f) / 3000.0f);
            out[(size_t)B * NA + b1] = fminf(0.95f, fmaxf(-0.95f, y));
        }
    }
}

extern "C" void kernel_launch(void* const* d_in, const int* in_sizes, int n_in,
                              void* d_out, int out_size, void* d_ws, size_t ws_size,
                              hipStream_t stream) {
    const int*   boards = (const int*)d_in[0];
    const int*   cur    = (const int*)d_in[1];
    const float* pn     = (const float*)d_in[2];
    const float* vn     = (const float*)d_in[3];
    float*       outp   = (float*)d_out;
    const int B = in_sizes[1];  // current_player has B elements

    const int grid = (B + 7) / 8;  // 8 boards per block (2 per wave)
    heur_kernel<<<grid, 256, 0, stream>>>(boards, cur, pn, vn, outp, B);
}